// Round 3
// baseline (4063.945 us; speedup 1.0000x reference)
//
#include <hip/hip_runtime.h>
#include <hip/hip_bf16.h>

typedef __hip_bfloat16 bf16;

#define B_  32
#define L_  144
#define D_  96
#define HW_ 64

// Kernel A tiling
#define TW  32          // tile width (pixels)
#define TH  16          // tile height
#define CCH 4           // input-channel chunk staged in LDS
#define DG  8           // output channels per block
#define PR  (TH + 6)    // 22 patch rows
#define PC  (TW + 6)    // 38 patch cols

#define FMA_Q(acc, off, xv, wv)                               \
    acc[(off)+0] = fmaf((xv), (wv).x, acc[(off)+0]);          \
    acc[(off)+1] = fmaf((xv), (wv).y, acc[(off)+1]);          \
    acc[(off)+2] = fmaf((xv), (wv).z, acc[(off)+2]);          \
    acc[(off)+3] = fmaf((xv), (wv).w, acc[(off)+3]);

// ---------------------------------------------------------------------------
// Kernel A: 3 branch convs (3x3/5x5/7x7 same-pad) + bias + BN(eval) + ReLU,
// fused into one 7x7 window walk with 3 accumulators. Emits add & max planes
// (avg folded into final conv weights since avg = add/3) as bf16, PACKED INTO
// d_out: plane p's 4096 fp32 slot holds [4096 x bf16 add][4096 x bf16 max].
// No workspace — removes any d_ws OOB risk (round-2 post-timing corruption).
// ---------------------------------------------------------------------------
__global__ __launch_bounds__(256) void branch_conv_kernel(
    const float* __restrict__ x,
    const float* __restrict__ w1, const float* __restrict__ b1,
    const float* __restrict__ g1, const float* __restrict__ be1,
    const float* __restrict__ m1, const float* __restrict__ v1,
    const float* __restrict__ w2, const float* __restrict__ b2,
    const float* __restrict__ g2, const float* __restrict__ be2,
    const float* __restrict__ m2, const float* __restrict__ v2,
    const float* __restrict__ w3, const float* __restrict__ b3,
    const float* __restrict__ g3, const float* __restrict__ be3,
    const float* __restrict__ m3, const float* __restrict__ v3,
    float* __restrict__ outp)
{
    const int t = threadIdx.x;
    const int TXc = t & 31;         // 0..31 (pixel col within tile)
    const int TYr = t >> 5;         // 0..7  (pixel row; 2nd pixel at +8)
    const int tile = blockIdx.x;    // 0..7  (2 wide x 4 tall)
    const int w0 = (tile & 1) * TW;
    const int h0 = (tile >> 1) * TH;
    const int b = blockIdx.y;
    const int dgBase = blockIdx.z * DG;

    __shared__ float patch[CCH * PR * PC];   // 3344 floats
    __shared__ float w3s[CCH * 49 * DG];     // [ (l*49+tap)*8 + d ]
    __shared__ float w2s[CCH * 25 * DG];
    __shared__ float w1s[CCH * 9 * DG];

    float a1[16], a2[16], a3[16];   // [px*8 + d], px in {0,1}
    #pragma unroll
    for (int q = 0; q < 16; ++q) { a1[q] = 0.f; a2[q] = 0.f; a3[q] = 0.f; }

    const int dqw = t >> 5;   // 0..7  : which d this thread stages
    const int lnw = t & 31;   // 0..31 : lane within the d-group

    for (int lc = 0; lc < L_; lc += CCH) {
        __syncthreads();
        // ---- stage input patch (zero-padded halo of 3) ----
        for (int i = t; i < CCH * PR * PC; i += 256) {
            const int c = i % PC;
            const int r = (i / PC) % PR;
            const int l = i / (PR * PC);
            const int gh = h0 - 3 + r, gw = w0 - 3 + c;
            float v = 0.f;
            if (gh >= 0 && gh < HW_ && gw >= 0 && gw < HW_)
                v = x[(((size_t)b * L_ + lc + l) * HW_ + gh) * HW_ + gw];
            patch[i] = v;
        }
        // ---- stage weights, transposed to [l][tap][d] for float4-over-d ----
        {
            const float* s3 = w3 + ((size_t)(dgBase + dqw) * L_ + lc) * 49;
            for (int i = lnw; i < CCH * 49; i += 32) w3s[i * DG + dqw] = s3[i];
            const float* s2 = w2 + ((size_t)(dgBase + dqw) * L_ + lc) * 25;
            for (int i = lnw; i < CCH * 25; i += 32) w2s[i * DG + dqw] = s2[i];
            const float* s1 = w1 + ((size_t)(dgBase + dqw) * L_ + lc) * 9;
            for (int i = lnw; i < CCH * 9; i += 32) w1s[i * DG + dqw] = s1[i];
        }
        __syncthreads();

        #pragma unroll 1
        for (int l = 0; l < CCH; ++l) {
            const float* prow0 = &patch[(l * PR + TYr) * PC + TXc];
            const float* prow1 = prow0 + 8 * PC;
            const float4* w3q = (const float4*)&w3s[l * 49 * DG];
            const float4* w2q = (const float4*)&w2s[l * 25 * DG];
            const float4* w1q = (const float4*)&w1s[l * 9 * DG];
            #pragma unroll
            for (int kh = 0; kh < 7; ++kh) {
                #pragma unroll
                for (int kw = 0; kw < 7; ++kw) {
                    const float xv0 = prow0[kh * PC + kw];
                    const float xv1 = prow1[kh * PC + kw];
                    {
                        const float4* wp = w3q + (kh * 7 + kw) * 2;
                        const float4 wa = wp[0], wb = wp[1];
                        FMA_Q(a3, 0, xv0, wa); FMA_Q(a3, 4, xv0, wb);
                        FMA_Q(a3, 8, xv1, wa); FMA_Q(a3, 12, xv1, wb);
                    }
                    if (kh >= 1 && kh <= 5 && kw >= 1 && kw <= 5) {
                        const float4* wp = w2q + ((kh - 1) * 5 + (kw - 1)) * 2;
                        const float4 wa = wp[0], wb = wp[1];
                        FMA_Q(a2, 0, xv0, wa); FMA_Q(a2, 4, xv0, wb);
                        FMA_Q(a2, 8, xv1, wa); FMA_Q(a2, 12, xv1, wb);
                    }
                    if (kh >= 2 && kh <= 4 && kw >= 2 && kw <= 4) {
                        const float4* wp = w1q + ((kh - 2) * 3 + (kw - 2)) * 2;
                        const float4 wa = wp[0], wb = wp[1];
                        FMA_Q(a1, 0, xv0, wa); FMA_Q(a1, 4, xv0, wb);
                        FMA_Q(a1, 8, xv1, wa); FMA_Q(a1, 12, xv1, wb);
                    }
                }
            }
        }
    }

    // ---- epilogue: bias+BN+ReLU per branch, then add & max, store bf16 ----
    #pragma unroll
    for (int q = 0; q < DG; ++q) {
        const int d = dgBase + q;
        const float i1 = g1[d] * rsqrtf(v1[d] + 1e-5f);
        const float c1 = fmaf(b1[d] - m1[d], i1, be1[d]);
        const float i2 = g2[d] * rsqrtf(v2[d] + 1e-5f);
        const float c2 = fmaf(b2[d] - m2[d], i2, be2[d]);
        const float i3 = g3[d] * rsqrtf(v3[d] + 1e-5f);
        const float c3 = fmaf(b3[d] - m3[d], i3, be3[d]);
        // plane slot: 4096 fp32 reinterpreted as [4096 bf16 add][4096 bf16 max]
        bf16* pl = (bf16*)(outp + (((size_t)b * D_ + d) << 12));
        #pragma unroll
        for (int px = 0; px < 2; ++px) {
            const float y1 = fmaxf(0.f, fmaf(a1[px * 8 + q], i1, c1));
            const float y2 = fmaxf(0.f, fmaf(a2[px * 8 + q], i2, c2));
            const float y3 = fmaxf(0.f, fmaf(a3[px * 8 + q], i3, c3));
            const float av = y1 + y2 + y3;
            const float mv = fmaxf(y1, fmaxf(y2, y3));
            const int h = h0 + TYr + px * 8;
            const int idx = (h << 6) + (w0 + TXc);
            pl[idx] = __float2bfloat16(av);
            pl[4096 + idx] = __float2bfloat16(mv);
        }
    }
}

// ---------------------------------------------------------------------------
// Kernel B: per-(b,d)-plane 3x3 conv over [add; max] with avg folded:
//   out = conv3x3(add, wf0 + wf1/3) + conv3x3(max, wf2), zero-padded.
// Reads the packed bf16 planes from its OWN d_out slot into LDS, then
// overwrites the slot in place with fp32 results (block-local, race-free).
// ---------------------------------------------------------------------------
__global__ __launch_bounds__(256) void fuse_kernel(
    const float* __restrict__ wf, float* __restrict__ out)
{
    const int p = blockIdx.x;      // plane = b*96 + d
    const int t = threadIdx.x;
    __shared__ float sa[66 * 66];
    __shared__ float sm[66 * 66];
    const bf16* base = (const bf16*)(out + ((size_t)p << 12));

    for (int i = t; i < 66 * 66; i += 256) {
        const int c = i % 66, r = i / 66;
        const int gh = r - 1, gw = c - 1;
        float va = 0.f, vm = 0.f;
        if (gh >= 0 && gh < 64 && gw >= 0 && gw < 64) {
            va = __bfloat162float(base[(gh << 6) + gw]);
            vm = __bfloat162float(base[4096 + (gh << 6) + gw]);
        }
        sa[i] = va; sm[i] = vm;
    }

    float wa[9], wm[9];
    #pragma unroll
    for (int j = 0; j < 9; ++j) {
        wa[j] = wf[j] + wf[9 + j] * (1.f / 3.f);
        wm[j] = wf[18 + j];
    }
    __syncthreads();   // all global reads done & staged before in-place write

    float* op = out + ((size_t)p << 12);
    for (int i = t; i < 4096; i += 256) {
        const int h = i >> 6, w = i & 63;
        float acc = 0.f;
        #pragma unroll
        for (int kh = 0; kh < 3; ++kh) {
            #pragma unroll
            for (int kw = 0; kw < 3; ++kw) {
                acc = fmaf(sa[(h + kh) * 66 + (w + kw)], wa[kh * 3 + kw], acc);
                acc = fmaf(sm[(h + kh) * 66 + (w + kw)], wm[kh * 3 + kw], acc);
            }
        }
        op[i] = acc;
    }
}

extern "C" void kernel_launch(void* const* d_in, const int* in_sizes, int n_in,
                              void* d_out, int out_size, void* d_ws, size_t ws_size,
                              hipStream_t stream)
{
    const float* x   = (const float*)d_in[0];
    const float* w1  = (const float*)d_in[1];
    const float* b1  = (const float*)d_in[2];
    const float* g1  = (const float*)d_in[3];
    const float* be1 = (const float*)d_in[4];
    const float* m1  = (const float*)d_in[5];
    const float* v1  = (const float*)d_in[6];
    const float* w2  = (const float*)d_in[7];
    const float* b2  = (const float*)d_in[8];
    const float* g2  = (const float*)d_in[9];
    const float* be2 = (const float*)d_in[10];
    const float* m2  = (const float*)d_in[11];
    const float* v2  = (const float*)d_in[12];
    const float* w3  = (const float*)d_in[13];
    const float* b3  = (const float*)d_in[14];
    const float* g3  = (const float*)d_in[15];
    const float* be3 = (const float*)d_in[16];
    const float* m3  = (const float*)d_in[17];
    const float* v3  = (const float*)d_in[18];
    const float* wf  = (const float*)d_in[19];
    float* out = (float*)d_out;

    (void)d_ws; (void)ws_size;   // unused — intermediates packed into d_out

    dim3 gridA(8, B_, D_ / DG);   // 8 spatial tiles x 32 batch x 12 d-groups
    branch_conv_kernel<<<gridA, 256, 0, stream>>>(
        x, w1, b1, g1, be1, m1, v1,
        w2, b2, g2, be2, m2, v2,
        w3, b3, g3, be3, m3, v3,
        out);

    fuse_kernel<<<B_ * D_, 256, 0, stream>>>(wf, out);
}

// Round 4
// 564.687 us; speedup vs baseline: 7.1968x; 7.1968x over previous
//
#include <hip/hip_runtime.h>
#include <hip/hip_bf16.h>

typedef __hip_bfloat16 bf16;
typedef short v8s __attribute__((ext_vector_type(8)));     // 8 bf16 (4 VGPRs)
typedef float f32x4 __attribute__((ext_vector_type(4)));   // MFMA acc

#define B_  32
#define L_  144
#define D_  96
#define HW_ 64

// main kernel geometry
#define PXROW 22                 // (16+6) patch rows/cols
#define PIXSTRIDE 80             // 32 l * 2B = 64B data + 16B pad (bank spread)
#define NPATCH (PXROW*PXROW*32)  // staged elements per l-chunk
#define WPACK_ELEMS (83*5*96*32) // packed bf16 weights

__device__ __forceinline__ unsigned short f2bf(float f) {
    union { float f; unsigned int u; } x{f};
    unsigned int r = x.u + 0x7fffu + ((x.u >> 16) & 1u);   // RNE
    return (unsigned short)(r >> 16);
}

// ---------------------------------------------------------------------------
// Weight prep: pack w1/w2/w3 (fp32, [D][L][k][k]) into A-fragment order bf16:
// wpack[((T*5+q)*96 + d)*32 + l~],  T: 0..48=7x7 taps, 49..73=5x5, 74..82=3x3,
// q = l-chunk (l = q*32+l~, zero-padded past 143).
// ---------------------------------------------------------------------------
__global__ __launch_bounds__(256) void prep_weights(
    const float* __restrict__ w1, const float* __restrict__ w2,
    const float* __restrict__ w3, unsigned short* __restrict__ wpack)
{
    int i = blockIdx.x * 256 + threadIdx.x;
    if (i >= WPACK_ELEMS) return;
    const int lt = i & 31;
    const int d  = (i >> 5) % 96;
    const int r  = (i >> 5) / 96;   // T*5 + q
    const int q  = r % 5;
    const int T  = r / 5;
    const int l  = q * 32 + lt;
    float v = 0.f;
    if (l < L_) {
        if (T < 49)      v = w3[(d * L_ + l) * 49 + T];
        else if (T < 74) v = w2[(d * L_ + l) * 25 + (T - 49)];
        else             v = w1[(d * L_ + l) * 9  + (T - 74)];
    }
    wpack[i] = f2bf(v);
}

// ---------------------------------------------------------------------------
// MFMA branch conv: 3 branch convs fused in one 7x7 tap walk over K=channels.
// Block: 96 d x (16x16 px), 8 waves = 2 d-halves x 4 px-quads.
// Wave: 3 d-tiles x 4 px-tiles x 3 branch accs (36 f32x4).
// Emits add/max bf16 planes packed into d_out (as round 3).
// ---------------------------------------------------------------------------
__global__ __launch_bounds__(512) void branch_conv_mfma(
    const float* __restrict__ x, const unsigned short* __restrict__ wpack,
    const float* __restrict__ b1, const float* __restrict__ g1,
    const float* __restrict__ be1, const float* __restrict__ m1,
    const float* __restrict__ v1,
    const float* __restrict__ b2, const float* __restrict__ g2,
    const float* __restrict__ be2, const float* __restrict__ m2,
    const float* __restrict__ v2,
    const float* __restrict__ b3, const float* __restrict__ g3,
    const float* __restrict__ be3, const float* __restrict__ m3,
    const float* __restrict__ v3,
    float* __restrict__ outp)
{
    __shared__ __align__(16) unsigned char patchB[PXROW * PXROW * PIXSTRIDE]; // 38720 B
    __shared__ float bns[96 * 6];

    const int t    = threadIdx.x;
    const int lane = t & 63;
    const int wid  = t >> 6;           // 0..7
    const int dhalf = wid >> 2;        // 0..1 -> d 0..47 / 48..95
    const int ptb   = (wid & 3) * 4;   // px-quad base row (0,4,8,12)
    const int lo = lane & 15;
    const int hi = lane >> 4;          // 0..3

    const int st = blockIdx.x;         // spatial tile 0..15
    const int h0 = (st >> 2) << 4;
    const int w0 = (st & 3) << 4;
    const int b  = blockIdx.y;

    // per-lane fragment offsets
    const int laneBoff = lo * PIXSTRIDE + hi * 16;         // bytes into patch pixel row
    const int laneAoff = lo * 32 + hi * 8;                 // elements into wpack block

    // BN constants -> LDS (visible after first barrier)
    if (t < 96) {
        const int d = t;
        const float i1 = g1[d] * rsqrtf(v1[d] + 1e-5f);
        const float i2 = g2[d] * rsqrtf(v2[d] + 1e-5f);
        const float i3 = g3[d] * rsqrtf(v3[d] + 1e-5f);
        bns[d*6+0] = i1; bns[d*6+1] = fmaf(b1[d] - m1[d], i1, be1[d]);
        bns[d*6+2] = i2; bns[d*6+3] = fmaf(b2[d] - m2[d], i2, be2[d]);
        bns[d*6+4] = i3; bns[d*6+5] = fmaf(b3[d] - m3[d], i3, be3[d]);
    }

    f32x4 acc3[3][4], acc2[3][4], acc1[3][4];
    #pragma unroll
    for (int dt = 0; dt < 3; ++dt)
        #pragma unroll
        for (int pp = 0; pp < 4; ++pp) {
            acc3[dt][pp] = (f32x4)0.f; acc2[dt][pp] = (f32x4)0.f; acc1[dt][pp] = (f32x4)0.f;
        }

    // wave-invariant weight base: + q*3072 added per chunk, + T*15360 per tap
    const unsigned short* wqBase = wpack + dhalf * 1536 + laneAoff;

    for (int q = 0; q < 5; ++q) {
        __syncthreads();
        // ---- stage patch chunk q: [pixel][32 l] bf16, 80B pixel stride ----
        for (int i = t; i < NPATCH; i += 512) {
            const int l   = i / 484;          // 0..31
            const int pix = i - l * 484;
            const int r = pix / PXROW, c = pix - r * PXROW;
            const int gh = h0 - 3 + r, gw = w0 - 3 + c;
            const int lg = q * 32 + l;
            float v = 0.f;
            if (lg < L_ && (unsigned)gh < 64u && (unsigned)gw < 64u)
                v = x[(((size_t)b * L_ + lg) << 12) + (gh << 6) + gw];
            *(unsigned short*)(patchB + pix * PIXSTRIDE + l * 2) = f2bf(v);
        }
        __syncthreads();

        const unsigned short* wq = wqBase + q * 3072;

        for (int kh = 0; kh < 7; ++kh) {
            const int rb0 = (ptb + kh) * PXROW;
            #pragma unroll
            for (int kw = 0; kw < 7; ++kw) {
                // B fragments: 4 px-tiles (rows), shared across branches
                v8s Bv[4];
                #pragma unroll
                for (int pp = 0; pp < 4; ++pp)
                    Bv[pp] = *(const v8s*)(patchB + (rb0 + pp * PXROW + kw) * PIXSTRIDE + laneBoff);

                // ---- branch 3 (7x7): every tap ----
                {
                    const unsigned short* wp = wq + (kh * 7 + kw) * 15360;
                    const v8s A0 = *(const v8s*)(wp);
                    const v8s A1 = *(const v8s*)(wp + 512);
                    const v8s A2 = *(const v8s*)(wp + 1024);
                    #pragma unroll
                    for (int pp = 0; pp < 4; ++pp) {
                        acc3[0][pp] = __builtin_amdgcn_mfma_f32_16x16x32_bf16(A0, Bv[pp], acc3[0][pp], 0, 0, 0);
                        acc3[1][pp] = __builtin_amdgcn_mfma_f32_16x16x32_bf16(A1, Bv[pp], acc3[1][pp], 0, 0, 0);
                        acc3[2][pp] = __builtin_amdgcn_mfma_f32_16x16x32_bf16(A2, Bv[pp], acc3[2][pp], 0, 0, 0);
                    }
                }
                // ---- branch 2 (5x5): central 5x5 taps ----
                if (kh >= 1 && kh <= 5 && kw >= 1 && kw <= 5) {
                    const unsigned short* wp = wq + (49 + (kh - 1) * 5 + (kw - 1)) * 15360;
                    const v8s A0 = *(const v8s*)(wp);
                    const v8s A1 = *(const v8s*)(wp + 512);
                    const v8s A2 = *(const v8s*)(wp + 1024);
                    #pragma unroll
                    for (int pp = 0; pp < 4; ++pp) {
                        acc2[0][pp] = __builtin_amdgcn_mfma_f32_16x16x32_bf16(A0, Bv[pp], acc2[0][pp], 0, 0, 0);
                        acc2[1][pp] = __builtin_amdgcn_mfma_f32_16x16x32_bf16(A1, Bv[pp], acc2[1][pp], 0, 0, 0);
                        acc2[2][pp] = __builtin_amdgcn_mfma_f32_16x16x32_bf16(A2, Bv[pp], acc2[2][pp], 0, 0, 0);
                    }
                }
                // ---- branch 1 (3x3): central 3x3 taps ----
                if (kh >= 2 && kh <= 4 && kw >= 2 && kw <= 4) {
                    const unsigned short* wp = wq + (74 + (kh - 2) * 3 + (kw - 2)) * 15360;
                    const v8s A0 = *(const v8s*)(wp);
                    const v8s A1 = *(const v8s*)(wp + 512);
                    const v8s A2 = *(const v8s*)(wp + 1024);
                    #pragma unroll
                    for (int pp = 0; pp < 4; ++pp) {
                        acc1[0][pp] = __builtin_amdgcn_mfma_f32_16x16x32_bf16(A0, Bv[pp], acc1[0][pp], 0, 0, 0);
                        acc1[1][pp] = __builtin_amdgcn_mfma_f32_16x16x32_bf16(A1, Bv[pp], acc1[1][pp], 0, 0, 0);
                        acc1[2][pp] = __builtin_amdgcn_mfma_f32_16x16x32_bf16(A2, Bv[pp], acc1[2][pp], 0, 0, 0);
                    }
                }
            }
        }
    }

    // ---- epilogue: BN+ReLU per branch, add & max, pack bf16 into d_out ----
    // C/D layout: col = lane&15 (pixel), row = hi*4 + reg (d within tile)
    #pragma unroll
    for (int dt = 0; dt < 3; ++dt) {
        #pragma unroll
        for (int reg = 0; reg < 4; ++reg) {
            const int d = dhalf * 48 + dt * 16 + hi * 4 + reg;
            const float i1 = bns[d*6+0], c1 = bns[d*6+1];
            const float i2 = bns[d*6+2], c2 = bns[d*6+3];
            const float i3 = bns[d*6+4], c3 = bns[d*6+5];
            unsigned short* pl = (unsigned short*)(outp + (((size_t)b * D_ + d) << 12));
            #pragma unroll
            for (int pp = 0; pp < 4; ++pp) {
                const float y1 = fmaxf(0.f, fmaf(acc1[dt][pp][reg], i1, c1));
                const float y2 = fmaxf(0.f, fmaf(acc2[dt][pp][reg], i2, c2));
                const float y3 = fmaxf(0.f, fmaf(acc3[dt][pp][reg], i3, c3));
                const float av = y1 + y2 + y3;
                const float mv = fmaxf(y1, fmaxf(y2, y3));
                const int h = h0 + ptb + pp;
                const int idx = (h << 6) + w0 + lo;
                pl[idx]        = f2bf(av);
                pl[4096 + idx] = f2bf(mv);
            }
        }
    }
}

// ---------------------------------------------------------------------------
// Kernel B: per-plane 3x3 conv over [add; max] with avg folded (unchanged).
// ---------------------------------------------------------------------------
__global__ __launch_bounds__(256) void fuse_kernel(
    const float* __restrict__ wf, float* __restrict__ out)
{
    const int p = blockIdx.x;      // plane = b*96 + d
    const int t = threadIdx.x;
    __shared__ float sa[66 * 66];
    __shared__ float sm[66 * 66];
    const bf16* base = (const bf16*)(out + ((size_t)p << 12));

    for (int i = t; i < 66 * 66; i += 256) {
        const int c = i % 66, r = i / 66;
        const int gh = r - 1, gw = c - 1;
        float va = 0.f, vm = 0.f;
        if (gh >= 0 && gh < 64 && gw >= 0 && gw < 64) {
            va = __bfloat162float(base[(gh << 6) + gw]);
            vm = __bfloat162float(base[4096 + (gh << 6) + gw]);
        }
        sa[i] = va; sm[i] = vm;
    }

    float wa[9], wm[9];
    #pragma unroll
    for (int j = 0; j < 9; ++j) {
        wa[j] = wf[j] + wf[9 + j] * (1.f / 3.f);
        wm[j] = wf[18 + j];
    }
    __syncthreads();

    float* op = out + ((size_t)p << 12);
    for (int i = t; i < 4096; i += 256) {
        const int h = i >> 6, w = i & 63;
        float acc = 0.f;
        #pragma unroll
        for (int kh = 0; kh < 3; ++kh) {
            #pragma unroll
            for (int kw = 0; kw < 3; ++kw) {
                acc = fmaf(sa[(h + kh) * 66 + (w + kw)], wa[kh * 3 + kw], acc);
                acc = fmaf(sm[(h + kh) * 66 + (w + kw)], wm[kh * 3 + kw], acc);
            }
        }
        op[i] = acc;
    }
}

extern "C" void kernel_launch(void* const* d_in, const int* in_sizes, int n_in,
                              void* d_out, int out_size, void* d_ws, size_t ws_size,
                              hipStream_t stream)
{
    const float* x   = (const float*)d_in[0];
    const float* w1  = (const float*)d_in[1];
    const float* b1  = (const float*)d_in[2];
    const float* g1  = (const float*)d_in[3];
    const float* be1 = (const float*)d_in[4];
    const float* m1  = (const float*)d_in[5];
    const float* v1  = (const float*)d_in[6];
    const float* w2  = (const float*)d_in[7];
    const float* b2  = (const float*)d_in[8];
    const float* g2  = (const float*)d_in[9];
    const float* be2 = (const float*)d_in[10];
    const float* m2  = (const float*)d_in[11];
    const float* v2  = (const float*)d_in[12];
    const float* w3  = (const float*)d_in[13];
    const float* b3  = (const float*)d_in[14];
    const float* g3  = (const float*)d_in[15];
    const float* be3 = (const float*)d_in[16];
    const float* m3  = (const float*)d_in[17];
    const float* v3  = (const float*)d_in[18];
    const float* wf  = (const float*)d_in[19];
    float* out = (float*)d_out;

    // d_ws: packed bf16 weights, 83*5*96*32*2B = 2.55 MB (rewritten every call)
    unsigned short* wpack = (unsigned short*)d_ws;

    prep_weights<<<(WPACK_ELEMS + 255) / 256, 256, 0, stream>>>(w1, w2, w3, wpack);

    dim3 gridA(16, B_);   // 16 spatial tiles (4x4 of 16x16) x 32 batch
    branch_conv_mfma<<<gridA, 512, 0, stream>>>(
        x, wpack,
        b1, g1, be1, m1, v1,
        b2, g2, be2, m2, v2,
        b3, g3, be3, m3, v3,
        out);

    fuse_kernel<<<B_ * D_, 256, 0, stream>>>(wf, out);
}